// Round 5
// baseline (57.304 us; speedup 1.0000x reference)
//
#include <hip/hip_runtime.h>
#include <math.h>

#define B_   4
#define C_   128
#define H_   96
#define W_   192
#define HW_  (H_*W_)

#define TH 8
#define TW 16
#define HX 18          // TW+2
#define HPX 180        // (TH+2)*HX

typedef __attribute__((ext_vector_type(8))) short bf16x8;
typedef __attribute__((ext_vector_type(4))) float f32x4;

__device__ __forceinline__ unsigned short f2bf(float f) {
    unsigned u = __float_as_uint(f);
    u = (u + 0x7FFFu + ((u >> 16) & 1u)) >> 16;   // RNE
    return (unsigned short)u;
}
__device__ __forceinline__ float bflo(unsigned u) { return __uint_as_float(u << 16); }
__device__ __forceinline__ float bfhi(unsigned u) { return __uint_as_float(u & 0xFFFF0000u); }

// ---------------------------------------------------------------------------
// prep: blocks 0..7 compute Mc = Wk^T Wq rows rb*16..+15 and write them
// directly in bf16 MFMA A-fragment order (no Mc HBM roundtrip):
//   Apack[((rb*4+ks)*64+lane)*8+j] = Mc[rb*16+(lane&15)][ks*32+(lane>>4)*8+j]
// block 8: u2 = Wk^T bq, v2 = Wq^T bk, c0 = bq.bk
// ---------------------------------------------------------------------------
__global__ __launch_bounds__(256) void prep_kernel(
    const float* __restrict__ Wq, const float* __restrict__ Wk,
    const float* __restrict__ bq, const float* __restrict__ bk,
    short* __restrict__ Apack, float* __restrict__ u2,
    float* __restrict__ v2, float* __restrict__ c0)
{
    if (blockIdx.x < 8) {
        const int rb   = blockIdx.x;
        const int t    = threadIdx.x;
        const int lane = t & 63;
        const int row  = rb * 16 + (lane & 15);
        const int colb = (t >> 6) * 32 + (lane >> 4) * 8;
        float a[8];
#pragma unroll
        for (int j = 0; j < 8; ++j) a[j] = 0.f;
        for (int c = 0; c < C_; ++c) {
            const float wk = Wk[c * C_ + row];
            const float4 w0 = *(const float4*)(Wq + c * C_ + colb);
            const float4 w1 = *(const float4*)(Wq + c * C_ + colb + 4);
            a[0] = fmaf(wk, w0.x, a[0]); a[1] = fmaf(wk, w0.y, a[1]);
            a[2] = fmaf(wk, w0.z, a[2]); a[3] = fmaf(wk, w0.w, a[3]);
            a[4] = fmaf(wk, w1.x, a[4]); a[5] = fmaf(wk, w1.y, a[5]);
            a[6] = fmaf(wk, w1.z, a[6]); a[7] = fmaf(wk, w1.w, a[7]);
        }
        bf16x8 v;
#pragma unroll
        for (int j = 0; j < 8; ++j) v[j] = (short)f2bf(a[j]);
        *(bf16x8*)(Apack + ((size_t)rb * 256 + t) * 8) = v;
    } else {
        const int t = threadIdx.x;
        if (t < 128) {
            float a = 0.f;
            for (int c = 0; c < C_; ++c) a = fmaf(Wk[c * C_ + t], bq[c], a);
            u2[t] = a;
        } else {
            const int i = t - 128;
            float a = 0.f;
            for (int c = 0; c < C_; ++c) a = fmaf(Wq[c * C_ + i], bk[c], a);
            v2[i] = a;
        }
        if (t == 0) {
            float a = 0.f;
            for (int c = 0; c < C_; ++c) a = fmaf(bq[c], bk[c], a);
            c0[0] = a;
        }
    }
}

// ---------------------------------------------------------------------------
// fused: stage f halo (bf16, swizzled) -> R = Mc f via MFMA -> per-wave LDS
// roundtrip repacks R into A-fragments -> band S-GEMMs (MFMA) vs halo ->
// 3-diagonal extraction into sS -> per-lane softmax + flow PV.
// Block = 8x16 px tile, 256 thr (4 waves; wave w owns tile rows 2w, 2w+1).
// LDS 66.5 KB -> 2 blocks/CU -> 2 waves/SIMD.
// ---------------------------------------------------------------------------
__global__ __launch_bounds__(256, 2) void fused_kernel(
    const float* __restrict__ f, const short* __restrict__ Apack,
    const float* __restrict__ u2v, const float* __restrict__ v2v,
    const float* __restrict__ c0p, const float* __restrict__ flow,
    float* __restrict__ out)
{
    __shared__ unsigned short sH[HPX * 128];    // 45 KB, chunk ^= px&15
    __shared__ unsigned short sA[4 * 16 * 136]; // 17 KB, per-wave r repack
    __shared__ float sS[TH][TW][9];             // 4.6 KB band scores

    const int t    = threadIdx.x;
    const int lane = t & 63;
    const int w    = t >> 6;
    const int g    = lane >> 4, p = lane & 15;

    const int wg  = blockIdx.x;                   // 576 = 8*72
    const int idx = (wg & 7) * 72 + (wg >> 3);    // XCD-band swizzle
    const int b   = idx / 144;
    const int rem = idx - b * 144;
    const int ty  = rem / 12, tx = rem - ty * 12;
    const int y0  = ty * TH, x0 = tx * TW;
    const float* fb = f + (size_t)b * C_ * HW_;

    // ---- stage halo: flat over (px, ch-octet), balanced across 256 thr ----
#pragma unroll
    for (int it = 0; it < 12; ++it) {
        const int gi = t + it * 256;
        if (gi < HPX * 16) {
            const int px = gi >> 4, c8 = gi & 15;
            const int hy = px / HX, hx = px - hy * HX;
            const int gy = y0 + hy - 1, gx = x0 + hx - 1;
            bf16x8 v = {0, 0, 0, 0, 0, 0, 0, 0};
            if ((gy >= 0) && (gy < H_) && (gx >= 0) && (gx < W_)) {
                const float* src = fb + gy * W_ + gx;
#pragma unroll
                for (int j = 0; j < 8; ++j)
                    v[j] = (short)f2bf(src[(size_t)(c8 * 8 + j) * HW_]);
            }
            *(bf16x8*)(sH + px * 128 + ((c8 ^ (px & 15)) * 8)) = v;
        }
    }
    __syncthreads();

    // ---- R-GEMM: wave w -> tile rows {2w, 2w+1}, 128 out-ch ----
    f32x4 acc[8][2];
#pragma unroll
    for (int rb = 0; rb < 8; ++rb)
#pragma unroll
        for (int cf = 0; cf < 2; ++cf) acc[rb][cf] = (f32x4){0.f, 0.f, 0.f, 0.f};

#pragma unroll
    for (int ks = 0; ks < 4; ++ks) {
        bf16x8 afr[8];
#pragma unroll
        for (int rb = 0; rb < 8; ++rb)
            afr[rb] = *(const bf16x8*)(Apack + ((size_t)((rb * 4 + ks) * 64 + lane)) * 8);
        bf16x8 bfr[2];
#pragma unroll
        for (int cf = 0; cf < 2; ++cf) {
            const int hpx = (2 * w + cf + 1) * HX + (p + 1);
            bfr[cf] = *(const bf16x8*)(sH + hpx * 128 + (((ks * 4 + g) ^ (hpx & 15)) * 8));
        }
#pragma unroll
        for (int rb = 0; rb < 8; ++rb)
#pragma unroll
            for (int cf = 0; cf < 2; ++cf)
                acc[rb][cf] = __builtin_amdgcn_mfma_f32_16x16x32_bf16(
                    afr[rb], bfr[cf], acc[rb][cf], 0, 0, 0);
    }

    // ---- repack R (C-frag, ch in 4-groups) -> A-frag (ch in 8-groups) via
    //      per-wave private LDS roundtrip; same-wave LDS is in-order. ----
    unsigned short* sAw = sA + w * (16 * 136);   // row stride 272 B (16-aligned)
    bf16x8 aS[2][4];
#pragma unroll
    for (int cf = 0; cf < 2; ++cf) {
#pragma unroll
        for (int rb = 0; rb < 8; ++rb) {
            const f32x4 uu = *(const f32x4*)(u2v + rb * 16 + g * 4);
            const f32x4 vv = acc[rb][cf] + uu;
            uint2 pk;
            pk.x = (unsigned)f2bf(vv[0]) | ((unsigned)f2bf(vv[1]) << 16);
            pk.y = (unsigned)f2bf(vv[2]) | ((unsigned)f2bf(vv[3]) << 16);
            *(uint2*)(sAw + p * 136 + rb * 16 + g * 4) = pk;
        }
#pragma unroll
        for (int ks = 0; ks < 4; ++ks)
            aS[cf][ks] = *(const bf16x8*)(sAw + p * 136 + ks * 32 + g * 8);
    }

    // ---- band S-GEMMs + 3-diagonal extraction ----
#pragma unroll
    for (int cf = 0; cf < 2; ++cf) {
        const int y = 2 * w + cf;
#pragma unroll
        for (int dy = 0; dy < 3; ++dy) {
            const int hyy = y + dy;
            f32x4 s0 = (f32x4){0.f, 0.f, 0.f, 0.f};
            f32x4 s1 = (f32x4){0.f, 0.f, 0.f, 0.f};
#pragma unroll
            for (int ks = 0; ks < 4; ++ks) {
                const int hpx0 = hyy * HX + p;       // ncol = hx-1 = p-1
                const int hpx1 = hpx0 + 2;           // ncol = p+1
                const bf16x8 b0 = *(const bf16x8*)(sH + hpx0 * 128 +
                                   (((ks * 4 + g) ^ (hpx0 & 15)) * 8));
                const bf16x8 b1 = *(const bf16x8*)(sH + hpx1 * 128 +
                                   (((ks * 4 + g) ^ (hpx1 & 15)) * 8));
                s0 = __builtin_amdgcn_mfma_f32_16x16x32_bf16(aS[cf][ks], b0, s0, 0, 0, 0);
                s1 = __builtin_amdgcn_mfma_f32_16x16x32_bf16(aS[cf][ks], b1, s1, 0, 0, 0);
            }
            // lane holds S[x = g*4+i][jj = p]; var0 serves x<=7, var1 x>=8
#pragma unroll
            for (int i = 0; i < 4; ++i) {
                const int x = g * 4 + i;
                const float val = (g < 2) ? s0[i] : s1[i];
                const int   d   = (g < 2) ? (p - x) : (x - p);
                const int   n9  = (g < 2) ? (dy * 3 + d) : (dy * 3 + 2 - d);
                if ((unsigned)d <= 2u) sS[y][x][n9] = val;
            }
        }
    }
    __syncthreads();

    // ---- softmax + flow PV: 2 lanes per px (v = lane>>5) ----
    const int r  = (lane >> 4) & 1;
    const int v  = lane >> 5;
    const int xl = lane & 15;
    const int yl = 2 * w + r;
    const int gy = y0 + yl, gx = x0 + xl;

    float beta = 0.f;
    const bool edge = (gx == 0) | (gx == W_ - 1) | (gy == 0) | (gy == H_ - 1);
    if (edge) {   // beta is softmax-invariant for interior pixels
        const int hpx = (yl + 1) * HX + (xl + 1);
#pragma unroll
        for (int c8 = 0; c8 < 16; ++c8) {
            const uint4 hv = *(const uint4*)(sH + hpx * 128 + ((c8 ^ (hpx & 15)) * 8));
            const float4 va = *(const float4*)(v2v + c8 * 8);
            const float4 vb = *(const float4*)(v2v + c8 * 8 + 4);
            beta += bflo(hv.x) * va.x + bfhi(hv.x) * va.y
                  + bflo(hv.y) * va.z + bfhi(hv.y) * va.w
                  + bflo(hv.z) * vb.x + bfhi(hv.z) * vb.y
                  + bflo(hv.w) * vb.z + bfhi(hv.w) * vb.w;
        }
        beta += *c0p;
    }

    const float scale = 0.08838834764831845f;   // 1/sqrt(128)
    float sv[9], mk[9];
    int spn[9];
    float m = -1e30f;
#pragma unroll
    for (int n = 0; n < 9; ++n) {
        const int yn = gy + n / 3 - 1, xn = gx + n % 3 - 1;
        const bool ok = (yn >= 0) && (yn < H_) && (xn >= 0) && (xn < W_);
        mk[n]  = ok ? 1.f : 0.f;
        spn[n] = ok ? yn * W_ + xn : gy * W_ + gx;
        sv[n]  = ok ? (sS[yl][xl][n] + beta) * scale : 0.f;
        m = fmaxf(m, sv[n]);
    }
    float e[9], sum = 0.f;
#pragma unroll
    for (int n = 0; n < 9; ++n) { e[n] = __expf(sv[n] - m); sum += e[n]; }
    const float inv = 1.f / sum;

    const float* f0 = flow + ((size_t)b * 2 + v) * HW_;
    float o = 0.f;
#pragma unroll
    for (int n = 0; n < 9; ++n) o += e[n] * mk[n] * f0[spn[n]];
    out[((size_t)b * 2 + v) * HW_ + gy * W_ + gx] = o * inv;
}

extern "C" void kernel_launch(void* const* d_in, const int* in_sizes, int n_in,
                              void* d_out, int out_size, void* d_ws, size_t ws_size,
                              hipStream_t stream) {
    const float* f   = (const float*)d_in[0];
    const float* flw = (const float*)d_in[1];
    const float* Wq  = (const float*)d_in[2];
    const float* bq  = (const float*)d_in[3];
    const float* Wk  = (const float*)d_in[4];
    const float* bk  = (const float*)d_in[5];
    float* out = (float*)d_out;

    short* Apack = (short*)d_ws;                  // 32 KB
    float* u2    = (float*)(Apack + 128 * 128);   // 512 B
    float* v2    = u2 + 128;                      // 512 B
    float* c0    = v2 + 128;                      // 4 B

    prep_kernel<<<9, 256, 0, stream>>>(Wq, Wk, bq, bk, Apack, u2, v2, c0);
    fused_kernel<<<576, 256, 0, stream>>>(f, Apack, u2, v2, c0, flw, out);
}

// Round 6
// 36.839 us; speedup vs baseline: 1.5555x; 1.5555x over previous
//
#include <hip/hip_runtime.h>
#include <math.h>

#define B_   4
#define C_   128
#define H_   96
#define W_   192
#define HW_  (H_*W_)

#define TH 8
#define TW 16
#define HX 18          // TW+2
#define HPX 180        // (TH+2)*HX
#define SHS 136        // sH row stride in shorts (272 B: 16B-aligned, 4-bank skew)

typedef __attribute__((ext_vector_type(8))) short bf16x8;
typedef __attribute__((ext_vector_type(4))) float f32x4;

__device__ __forceinline__ unsigned short f2bf(float f) {
    unsigned u = __float_as_uint(f);
    u = (u + 0x7FFFu + ((u >> 16) & 1u)) >> 16;   // RNE
    return (unsigned short)u;
}
__device__ __forceinline__ float bflo(unsigned u) { return __uint_as_float(u << 16); }
__device__ __forceinline__ float bfhi(unsigned u) { return __uint_as_float(u & 0xFFFF0000u); }

// ---------------------------------------------------------------------------
// prep: blocks 0..7 compute Mc = Wk^T Wq rows rb*16..+15, written directly in
// bf16 MFMA A-fragment order. block 8: u2 = Wk^T bq, v2 = Wq^T bk, c0 = bq.bk
// ---------------------------------------------------------------------------
__global__ __launch_bounds__(256) void prep_kernel(
    const float* __restrict__ Wq, const float* __restrict__ Wk,
    const float* __restrict__ bq, const float* __restrict__ bk,
    short* __restrict__ Apack, float* __restrict__ u2,
    float* __restrict__ v2, float* __restrict__ c0)
{
    if (blockIdx.x < 8) {
        const int rb   = blockIdx.x;
        const int t    = threadIdx.x;
        const int lane = t & 63;
        const int row  = rb * 16 + (lane & 15);
        const int colb = (t >> 6) * 32 + (lane >> 4) * 8;
        float a[8];
#pragma unroll
        for (int j = 0; j < 8; ++j) a[j] = 0.f;
        for (int c = 0; c < C_; ++c) {
            const float wk = Wk[c * C_ + row];
            const float4 w0 = *(const float4*)(Wq + c * C_ + colb);
            const float4 w1 = *(const float4*)(Wq + c * C_ + colb + 4);
            a[0] = fmaf(wk, w0.x, a[0]); a[1] = fmaf(wk, w0.y, a[1]);
            a[2] = fmaf(wk, w0.z, a[2]); a[3] = fmaf(wk, w0.w, a[3]);
            a[4] = fmaf(wk, w1.x, a[4]); a[5] = fmaf(wk, w1.y, a[5]);
            a[6] = fmaf(wk, w1.z, a[6]); a[7] = fmaf(wk, w1.w, a[7]);
        }
        bf16x8 v;
#pragma unroll
        for (int j = 0; j < 8; ++j) v[j] = (short)f2bf(a[j]);
        *(bf16x8*)(Apack + ((size_t)rb * 256 + t) * 8) = v;
    } else {
        const int t = threadIdx.x;
        if (t < 128) {
            float a = 0.f;
            for (int c = 0; c < C_; ++c) a = fmaf(Wk[c * C_ + t], bq[c], a);
            u2[t] = a;
        } else {
            const int i = t - 128;
            float a = 0.f;
            for (int c = 0; c < C_; ++c) a = fmaf(Wq[c * C_ + i], bk[c], a);
            v2[i] = a;
        }
        if (t == 0) {
            float a = 0.f;
            for (int c = 0; c < C_; ++c) a = fmaf(bq[c], bk[c], a);
            c0[0] = a;
        }
    }
}

// ---------------------------------------------------------------------------
// fused: coalesced-stage f halo (bf16, padded stride) -> R = Mc f via MFMA ->
// in-register C->A repack (ds_bpermute) -> band S-GEMMs -> 3-diagonal
// extraction -> per-lane softmax + flow PV.
// Block = 8x16 px tile, 256 thr (4 waves; wave w owns tile rows 2w, 2w+1).
// LDS 53.6 KB -> 3 blocks/CU -> 768 slots >= 576 blocks (single round).
// ---------------------------------------------------------------------------
__global__ __launch_bounds__(256, 3) void fused_kernel(
    const float* __restrict__ f, const short* __restrict__ Apack,
    const float* __restrict__ u2v, const float* __restrict__ v2v,
    const float* __restrict__ c0p, const float* __restrict__ flow,
    float* __restrict__ out)
{
    __shared__ unsigned short sH[HPX * SHS];    // 48960 B
    __shared__ float sS[TH][TW][9];             // 4608 B

    const int t    = threadIdx.x;
    const int lane = t & 63;
    const int w    = t >> 6;
    const int g    = lane >> 4, p = lane & 15;

    const int wg  = blockIdx.x;                   // 576 = 8*72
    const int idx = (wg & 7) * 72 + (wg >> 3);    // XCD-band swizzle
    const int b   = idx / 144;
    const int rem = idx - b * 144;
    const int ty  = rem / 12, tx = rem - ty * 12;
    const int y0  = ty * TH, x0 = tx * TW;
    const float* fb = f + (size_t)b * C_ * HW_;

    // ---- stage halo, px lane-minor (coalesced): gi -> (c8 = gi/180, px) ----
#pragma unroll
    for (int it = 0; it < 12; ++it) {
        const int gi = it * 256 + t;
        if (gi < HPX * 16) {
            const int c8 = gi / HPX;
            const int px = gi - c8 * HPX;
            const int hy = px / HX;
            const int hx = px - hy * HX;
            const int gy = y0 + hy - 1, gx = x0 + hx - 1;
            bf16x8 v = {0, 0, 0, 0, 0, 0, 0, 0};
            if ((gy >= 0) && (gy < H_) && (gx >= 0) && (gx < W_)) {
                const float* src = fb + gy * W_ + gx;
#pragma unroll
                for (int j = 0; j < 8; ++j)
                    v[j] = (short)f2bf(src[(size_t)(c8 * 8 + j) * HW_]);
            }
            *(bf16x8*)(sH + px * SHS + c8 * 8) = v;
        }
    }
    __syncthreads();

    // ---- R-GEMM: wave w -> tile rows {2w, 2w+1}, all 128 out-ch ----
    f32x4 acc[8][2];
#pragma unroll
    for (int rb = 0; rb < 8; ++rb)
#pragma unroll
        for (int cf = 0; cf < 2; ++cf) acc[rb][cf] = (f32x4){0.f, 0.f, 0.f, 0.f};

#pragma unroll
    for (int ks = 0; ks < 4; ++ks) {
        bf16x8 afr[8];
#pragma unroll
        for (int rb = 0; rb < 8; ++rb)
            afr[rb] = *(const bf16x8*)(Apack + ((size_t)((rb * 4 + ks) * 64 + lane)) * 8);
        bf16x8 bfr[2];
#pragma unroll
        for (int cf = 0; cf < 2; ++cf) {
            const int hpx = (2 * w + cf + 1) * HX + (p + 1);
            bfr[cf] = *(const bf16x8*)(sH + hpx * SHS + (ks * 4 + g) * 8);
        }
#pragma unroll
        for (int rb = 0; rb < 8; ++rb)
#pragma unroll
            for (int cf = 0; cf < 2; ++cf)
                acc[rb][cf] = __builtin_amdgcn_mfma_f32_16x16x32_bf16(
                    afr[rb], bfr[cf], acc[rb][cf], 0, 0, 0);
    }

    // ---- in-register repack C-frag -> A-frag (16-lane-group permute) ----
    // A-frag[ks] dword dd (ch pair ks*32+g*8+2dd) comes from lane
    // (2*(g&1)+(dd>>1))*16+p, reg pk[2ks+(g>>1)], dword (dd&1).
    const int L0 = ((lane & 16) << 1) | p;    // 2*(g&1)*16 + p
    const int L1 = L0 + 16;
    bf16x8 aS[2][4];
#pragma unroll
    for (int cf = 0; cf < 2; ++cf) {
        uint2 pk[8];
#pragma unroll
        for (int rb = 0; rb < 8; ++rb) {
            const f32x4 uu = *(const f32x4*)(u2v + rb * 16 + g * 4);
            const f32x4 vv = acc[rb][cf] + uu;
            pk[rb].x = (unsigned)f2bf(vv[0]) | ((unsigned)f2bf(vv[1]) << 16);
            pk[rb].y = (unsigned)f2bf(vv[2]) | ((unsigned)f2bf(vv[3]) << 16);
        }
#pragma unroll
        for (int ks = 0; ks < 4; ++ks) {
            int dw[4];
#pragma unroll
            for (int dd = 0; dd < 4; ++dd) {
                const int v0 = (dd & 1) ? (int)pk[2 * ks].y     : (int)pk[2 * ks].x;
                const int v1 = (dd & 1) ? (int)pk[2 * ks + 1].y : (int)pk[2 * ks + 1].x;
                const int sl = (dd & 2) ? L1 : L0;
                const int w0 = __shfl(v0, sl, 64);
                const int w1 = __shfl(v1, sl, 64);
                dw[dd] = (g & 2) ? w1 : w0;
            }
            int4 qv = make_int4(dw[0], dw[1], dw[2], dw[3]);
            aS[cf][ks] = *(bf16x8*)&qv;
        }
    }

    // ---- band S-GEMMs + 3-diagonal extraction ----
#pragma unroll
    for (int cf = 0; cf < 2; ++cf) {
        const int y = 2 * w + cf;
#pragma unroll
        for (int dy = 0; dy < 3; ++dy) {
            const int hyy = y + dy;
            f32x4 s0 = (f32x4){0.f, 0.f, 0.f, 0.f};
            f32x4 s1 = (f32x4){0.f, 0.f, 0.f, 0.f};
#pragma unroll
            for (int ks = 0; ks < 4; ++ks) {
                const int hpx0 = hyy * HX + p;       // ncol = p-1
                const bf16x8 b0 = *(const bf16x8*)(sH + hpx0 * SHS + (ks * 4 + g) * 8);
                const bf16x8 b1 = *(const bf16x8*)(sH + (hpx0 + 2) * SHS + (ks * 4 + g) * 8);
                s0 = __builtin_amdgcn_mfma_f32_16x16x32_bf16(aS[cf][ks], b0, s0, 0, 0, 0);
                s1 = __builtin_amdgcn_mfma_f32_16x16x32_bf16(aS[cf][ks], b1, s1, 0, 0, 0);
            }
#pragma unroll
            for (int i = 0; i < 4; ++i) {
                const int x = g * 4 + i;
                const float val = (g < 2) ? s0[i] : s1[i];
                const int   d   = (g < 2) ? (p - x) : (x - p);
                const int   n9  = (g < 2) ? (dy * 3 + d) : (dy * 3 + 2 - d);
                if ((unsigned)d <= 2u) sS[y][x][n9] = val;
            }
        }
    }
    // no barrier: sS rows {2w,2w+1} produced and consumed by the same wave

    // ---- softmax + flow PV: 2 lanes per px (v = lane>>5) ----
    const int r  = (lane >> 4) & 1;
    const int v  = lane >> 5;
    const int xl = lane & 15;
    const int yl = 2 * w + r;
    const int gy = y0 + yl, gx = x0 + xl;

    float beta = 0.f;
    const bool edge = (gx == 0) | (gx == W_ - 1) | (gy == 0) | (gy == H_ - 1);
    if (edge) {   // beta is softmax-invariant for interior pixels
        const int hpx = (yl + 1) * HX + (xl + 1);
#pragma unroll
        for (int c8 = 0; c8 < 16; ++c8) {
            const uint4 hv = *(const uint4*)(sH + hpx * SHS + c8 * 8);
            const float4 va = *(const float4*)(v2v + c8 * 8);
            const float4 vb = *(const float4*)(v2v + c8 * 8 + 4);
            beta += bflo(hv.x) * va.x + bfhi(hv.x) * va.y
                  + bflo(hv.y) * va.z + bfhi(hv.y) * va.w
                  + bflo(hv.z) * vb.x + bfhi(hv.z) * vb.y
                  + bflo(hv.w) * vb.z + bfhi(hv.w) * vb.w;
        }
        beta += *c0p;
    }

    const float scale = 0.08838834764831845f;   // 1/sqrt(128)
    float sv[9], mk[9];
    int spn[9];
    float m = -1e30f;
#pragma unroll
    for (int n = 0; n < 9; ++n) {
        const int yn = gy + n / 3 - 1, xn = gx + n % 3 - 1;
        const bool ok = (yn >= 0) && (yn < H_) && (xn >= 0) && (xn < W_);
        mk[n]  = ok ? 1.f : 0.f;
        spn[n] = ok ? yn * W_ + xn : gy * W_ + gx;
        sv[n]  = ok ? (sS[yl][xl][n] + beta) * scale : 0.f;
        m = fmaxf(m, sv[n]);
    }
    float e[9], sum = 0.f;
#pragma unroll
    for (int n = 0; n < 9; ++n) { e[n] = __expf(sv[n] - m); sum += e[n]; }
    const float inv = 1.f / sum;

    const float* f0 = flow + ((size_t)b * 2 + v) * HW_;
    float o = 0.f;
#pragma unroll
    for (int n = 0; n < 9; ++n) o += e[n] * mk[n] * f0[spn[n]];
    out[((size_t)b * 2 + v) * HW_ + gy * W_ + gx] = o * inv;
}

extern "C" void kernel_launch(void* const* d_in, const int* in_sizes, int n_in,
                              void* d_out, int out_size, void* d_ws, size_t ws_size,
                              hipStream_t stream) {
    const float* f   = (const float*)d_in[0];
    const float* flw = (const float*)d_in[1];
    const float* Wq  = (const float*)d_in[2];
    const float* bq  = (const float*)d_in[3];
    const float* Wk  = (const float*)d_in[4];
    const float* bk  = (const float*)d_in[5];
    float* out = (float*)d_out;

    short* Apack = (short*)d_ws;                  // 32 KB
    float* u2    = (float*)(Apack + 128 * 128);   // 512 B
    float* v2    = u2 + 128;                      // 512 B
    float* c0    = v2 + 128;                      // 4 B

    prep_kernel<<<9, 256, 0, stream>>>(Wq, Wk, bq, bk, Apack, u2, v2, c0);
    fused_kernel<<<576, 256, 0, stream>>>(f, Apack, u2, v2, c0, flw, out);
}